// Round 1
// 404.865 us; speedup vs baseline: 1.0542x; 1.0542x over previous
//
#include <hip/hip_runtime.h>

// Problem constants (baked per reference)
#define SEQ        300
#define V4         (SEQ / 4)          // 75 float4 per row (1200 B rows, 16B aligned)
#define NROWS      (192 * 32 * 32)    // (F*fs, y, x) rows = 196608
#define N4         (NROWS * V4)       // 14,745,600 float4 elements
#define NFRAMES    24
#define UNROLL     4
#define TTOT       (N4 / UNROLL)      // 3,686,400 threads total
#define P1BLOCKS   (TTOT / 256)       // 14400 blocks
#define ROWSTEP    (TTOT / V4)        // 49152 rows per j-step (exact)
#define FSTEP      (ROWSTEP >> 13)    // 6 frames per j-step (exact, low 13 bits zero)

typedef float f32x4 __attribute__((ext_vector_type(4)));

// Bbox per frame: top=8, bottom=24 always; left/width from int(32*ratio) truncation
__constant__ int c_left[NFRAMES]  = {1,2,2,3,4,5,5,6,7,7,8,9,9,10,11,12,12,13,14,14,15,16,16,17};
__constant__ int c_width[NFRAMES] = {10,9,10,10,9,9,10,10,9,10,10,9,10,10,9,9,10,10,9,10,10,9,10,10};

// Per-c (float4 column group) weaken factors. Token set = {2,3} ∪ [9,108].
// c=0 -> s 0..3: {1,1,w,w}; c=1 -> s 4..7: ones; c=2 -> s 8..11: {1,w,w,w};
// c=3..26 -> fully inside [9,108]: all w; c=27 -> s 108..111: {w,1,1,1}; c>=28: ones.
#define Wq 0.918f
#define W4 Wq,Wq,Wq,Wq,
#define O4 1.0f,1.0f,1.0f,1.0f,
__constant__ __align__(16) float c_wf[300] = {
    1.0f,1.0f,Wq,Wq,      // c=0
    O4                    // c=1
    1.0f,Wq,Wq,Wq,        // c=2
    W4 W4 W4 W4 W4 W4 W4 W4 W4 W4 W4 W4
    W4 W4 W4 W4 W4 W4 W4 W4 W4 W4 W4 W4   // c=3..26 (24 entries)
    Wq,1.0f,1.0f,1.0f,    // c=27
    O4 O4 O4 O4 O4 O4 O4 O4 O4 O4 O4 O4
    O4 O4 O4 O4 O4 O4 O4 O4 O4 O4 O4 O4
    O4 O4 O4 O4 O4 O4 O4 O4 O4 O4 O4 O4
    O4 O4 O4 O4 O4 O4 O4 O4 O4 O4 O4      // c=28..74 (47 entries)
};

__device__ __forceinline__ float wave_max64(float v) {
    #pragma unroll
    for (int off = 32; off > 0; off >>= 1)
        v = fmaxf(v, __shfl_down(v, off, 64));
    return v;
}

// Phase 1: fused weaken-apply + per-block max of raw input.
// 4 float4/thread, stride TTOT. Because TTOT % 75 == 0 and TTOT/75 = 49152 =
// 6*8192, all j-steps share (c, yy, xx) and only f advances by 6 per step.
__global__ void __launch_bounds__(256) kphase1(const f32x4* __restrict__ in,
                                               f32x4* __restrict__ out,
                                               float* __restrict__ bmax) {
    const int t    = blockIdx.x * 256 + threadIdx.x;
    const int row0 = t / V4;
    const int c    = t - row0 * V4;
    const int f0   = row0 >> 13;
    const int yy   = (row0 >> 5) & 31;
    const int xx   = row0 & 31;
    const bool yIn = (yy >= 8) & (yy < 24);
    const f32x4 wf = ((const f32x4*)c_wf)[c];

    f32x4 v[UNROLL];
    #pragma unroll
    for (int j = 0; j < UNROLL; j++)
        v[j] = __builtin_nontemporal_load(in + t + j * TTOT);

    float m = 0.0f;
    #pragma unroll
    for (int j = 0; j < UNROLL; j++) {
        f32x4 x = v[j];
        m = fmaxf(m, fmaxf(fmaxf(x[0], x[1]), fmaxf(x[2], x[3])));
        const int f = f0 + j * FSTEP;
        const int l = c_left[f];
        const bool inB = yIn & (xx >= l) & (xx < l + c_width[f]);
        f32x4 r = inB ? x : (x * wf);
        __builtin_nontemporal_store(r, out + t + j * TTOT);
    }

    // block max -> partials
    m = wave_max64(m);
    __shared__ float sw[4];
    const int lane = threadIdx.x & 63, wv = threadIdx.x >> 6;
    if (lane == 0) sw[wv] = m;
    __syncthreads();
    if (threadIdx.x == 0)
        bmax[blockIdx.x] = fmaxf(fmaxf(sw[0], sw[1]), fmaxf(sw[2], sw[3]));
}

// Phase 2: one block per frame. Reduce global max over 14400 partials, build
// normalized gaussian patch in LDS, write the frame's 32x32 weight-map slice.
__global__ void kwm(const float* __restrict__ bmax, float* __restrict__ wm) {
    __shared__ float patch[16 * 10];
    __shared__ float sw[4];
    __shared__ float s_scale, s_gmax;
    const int f = blockIdx.x;
    const int tid = threadIdx.x;   // 256 threads

    float m = 0.0f;
    for (int i = tid; i < P1BLOCKS; i += 256) m = fmaxf(m, bmax[i]);
    m = wave_max64(m);
    if ((tid & 63) == 0) sw[tid >> 6] = m;
    __syncthreads();
    if (tid == 0) s_scale = fmaxf(fmaxf(sw[0], sw[1]), fmaxf(sw[2], sw[3]));  // INJECTION_SCALE=1

    const int w = c_width[f], l = c_left[f];
    if (tid < 16 * w) {
        int i = tid / w, j = tid - i * w;
        float x = (float)i * (16.0f / 15.0f);
        float y = (float)j * ((float)w / (float)(w - 1));
        float dx = x - 8.0f;                 // h//2
        float dy = y - (float)(w / 2);       // w//2
        float sx = 16.0f / 3.0f;
        float sy = (float)w / 3.0f;
        patch[tid] = expf(-(dx * dx / (2.0f * sx * sx) + dy * dy / (2.0f * sy * sy)));
    }
    __syncthreads();
    if (tid == 0) {
        float g = 0.0f;
        for (int k = 0; k < 16 * w; k++) g = fmaxf(g, patch[k]);
        s_gmax = g;
    }
    __syncthreads();
    const float mul = s_scale / s_gmax;
    for (int p = tid; p < 1024; p += 256) {
        int yy = p >> 5, xx = p & 31;
        float v = 0.0f;
        if (yy >= 8 && yy < 24 && xx >= l && xx < l + w)
            v = patch[(yy - 8) * w + (xx - l)] * mul;
        wm[f * 1024 + p] = v;
    }
}

// Phase 3: add 0.125*wm to the bbox ∩ selected-token region only.
// Grid: 24 frames × 8 fs × 16 bbox rows = 3072 blocks. Each block handles
// w (9-10) x-positions × 102 tokens ≈ 1020 elems (L2-hot RMW).
__global__ void kinject(float* __restrict__ out, const float* __restrict__ wm) {
    const int b  = blockIdx.x;
    const int f  = b >> 7;            // /128
    const int fs = (b >> 4) & 7;
    const int yy = (b & 15) + 8;
    const int l  = c_left[f], w = c_width[f];
    const int r0 = ((f * 8 + fs) * 32 + yy) * 32;   // row index of (x=0)
    const int total = w * 102;

    for (int t = threadIdx.x; t < total; t += 256) {
        int xi = t / 102;
        int si = t - xi * 102;
        int s  = (si < 2) ? (si + 2) : (si + 7);    // {2,3} ∪ [9,108]
        float add = 0.125f * wm[f * 1024 + yy * 32 + l + xi];
        out[(r0 + l + xi) * SEQ + s] += add;
    }
}

extern "C" void kernel_launch(void* const* d_in, const int* in_sizes, int n_in,
                              void* d_out, int out_size, void* d_ws, size_t ws_size,
                              hipStream_t stream) {
    const float* ap = (const float*)d_in[0];
    float* out = (float*)d_out;
    float* ws  = (float*)d_ws;
    float* bmax = ws;               // 14400 floats
    float* wm   = ws + P1BLOCKS;    // 24*1024 floats

    kphase1<<<P1BLOCKS, 256, 0, stream>>>((const f32x4*)ap, (f32x4*)out, bmax);
    kwm<<<NFRAMES, 256, 0, stream>>>(bmax, wm);
    kinject<<<24 * 8 * 16, 256, 0, stream>>>(out, wm);
}